// Round 5
// baseline (938.626 us; speedup 1.0000x reference)
//
#include <hip/hip_runtime.h>

typedef __bf16 bf16_t;
typedef __bf16 bf16x8 __attribute__((ext_vector_type(8)));
typedef __bf16 bf16x4 __attribute__((ext_vector_type(4)));
typedef float f32x4 __attribute__((ext_vector_type(4)));
typedef int i32x4 __attribute__((ext_vector_type(4)));

#define BM 64
// Fused layer kernel: phase-1 RGC GEMM (A[M,K] x Wt[256,K]^T) -> h (LDS only),
// phase-2 highway GEMM (h x Wht[512,256]^T) + gate -> output. h never hits HBM.
// Weights are L2-resident (<=640 KB) -> B-fragments read directly from global;
// only the 4 KB A-tile is LDS-staged (double-buffered, 1 barrier/K-step).
// Paired-row LDS layout for A/h tiles: rows 2L,2L+1 share a 128 B line; chunk
// (row parity p, k-chunk q) at slot ((p<<2)|q)^(L&7) -> 3-bit XOR bank spread.
// DMA writes lane*16 contiguously (m104/m108): we permute WHICH global chunk
// each lane loads.

__device__ __forceinline__ void gload_lds16(const void* g, void* s) {
    __builtin_amdgcn_global_load_lds(
        (const __attribute__((address_space(1))) unsigned int*)g,
        (__attribute__((address_space(3))) unsigned int*)s, 16, 0, 0);
}

// chunk index g (8 chunks per 2-row line) -> (row, kcol) for a 64x32 tile
__device__ __forceinline__ void chunk_map(int g, int& row, int& kcol) {
    int L = g >> 3;
    int v = (g & 7) ^ (L & 7);
    row  = 2 * L + (v >> 2);
    kcol = (v & 3) << 3;
}

// fragment LDS element offset for (r, quad) in a 64x32 tile
__device__ __forceinline__ int frag_off(int r, int quad) {
    int L = r >> 1;
    return L * 64 + (((((r & 1) << 2) | quad) ^ (L & 7)) << 3);
}

// scalar element offset for (row, col 0..255) in the 8-slab Hs region
__device__ __forceinline__ int hs_off(int row, int col) {
    int L = row >> 1;
    int kin = col & 31;
    return (col >> 5) * 2048 + L * 64 +
           (((((row & 1) << 2) | (kin >> 3)) ^ (L & 7)) << 3) + (kin & 7);
}

// ---------------- fused RGC-GEMM + highway ----------------
// Block: 64 rows x 256 h-cols. 4 waves (2x2) in phase 1: wave tile 32x128,
// acc1[2][8]=64 VGPRs, B reg-pipelined 2 deep. Phase 2: wave = 16 rows x
// (128 P + 128 G) per strip, acc2[16]=64 VGPRs, no barriers.
__global__ __launch_bounds__(256, 3) void gemm_fused(
    const bf16_t* __restrict__ A, int lda, int M, int K,
    const bf16_t* __restrict__ Wt,    // [256, K] rel|loop weights, k-major
    const float* __restrict__ bR,     // [256] phase-1 bias
    const bf16_t* __restrict__ Wht,   // [512, 256] = [hp rows | ht rows]
    const float* __restrict__ bH,     // [512] = [hp bias | ht bias]
    bf16_t* __restrict__ outb, int ldo, int ocol,
    float* __restrict__ outf, int NTM)
{
    __shared__ __align__(16) bf16_t As[2][64 * 32];   // 2 x 4 KB
    __shared__ __align__(16) bf16_t Hs[8 * 64 * 32];  // 32 KB (8 k-slabs of h)

    const int Lb  = blockIdx.x;
    const int xcd = Lb & 7;
    const int sup = Lb >> 3;
    const int mt  = sup * 8 + xcd;
    if (mt >= NTM) return;
    const int m0 = mt * BM;

    const int tid  = threadIdx.x;
    const int wave = tid >> 6, lane = tid & 63;
    const int wr   = wave >> 1, wc = wave & 1;
    const int lm   = lane & 15, quad = lane >> 4;

    const bf16_t* ag;
    {
        int row, kcol; chunk_map(tid, row, kcol);
        int gm = m0 + row; if (gm >= M) gm = M - 1;
        ag = A + (size_t)gm * lda + kcol;
    }
    const bf16_t* bbase = Wt + (size_t)(wc * 128 + lm) * K + quad * 8;

    f32x4 acc1[2][8] = {};
    const int nt = K >> 5;   // 20 or 40 (even)

    bf16x8 b0[8], b1[8];
    #pragma unroll
    for (int ni = 0; ni < 8; ni++)
        b0[ni] = *(const bf16x8*)(bbase + (size_t)ni * 16 * K);

    gload_lds16(ag, &As[0][tid * 8]);
    __syncthreads();

    for (int t = 0; t < nt; t += 2) {
        // ---- step t (buf 0) ----
        #pragma unroll
        for (int ni = 0; ni < 8; ni++)
            b1[ni] = *(const bf16x8*)(bbase + (size_t)ni * 16 * K + (t + 1) * 32);
        gload_lds16(ag + (t + 1) * 32, &As[1][tid * 8]);
        {
            bf16x8 af[2];
            #pragma unroll
            for (int i = 0; i < 2; i++)
                af[i] = *(const bf16x8*)&As[0][frag_off(wr * 32 + i * 16 + lm, quad)];
            #pragma unroll
            for (int ni = 0; ni < 8; ni++)
                #pragma unroll
                for (int mi = 0; mi < 2; mi++)
                    acc1[mi][ni] = __builtin_amdgcn_mfma_f32_16x16x32_bf16(
                        af[mi], b0[ni], acc1[mi][ni], 0, 0, 0);
        }
        __syncthreads();
        // ---- step t+1 (buf 1) ----
        if (t + 2 < nt) {
            #pragma unroll
            for (int ni = 0; ni < 8; ni++)
                b0[ni] = *(const bf16x8*)(bbase + (size_t)ni * 16 * K + (t + 2) * 32);
            gload_lds16(ag + (t + 2) * 32, &As[0][tid * 8]);
        }
        {
            bf16x8 af[2];
            #pragma unroll
            for (int i = 0; i < 2; i++)
                af[i] = *(const bf16x8*)&As[1][frag_off(wr * 32 + i * 16 + lm, quad)];
            #pragma unroll
            for (int ni = 0; ni < 8; ni++)
                #pragma unroll
                for (int mi = 0; mi < 2; mi++)
                    acc1[mi][ni] = __builtin_amdgcn_mfma_f32_16x16x32_bf16(
                        af[mi], b1[ni], acc1[mi][ni], 0, 0, 0);
        }
        __syncthreads();
    }

    // ---- h = relu(acc1 + bR) -> bf16 -> Hs (LDS only) ----
    #pragma unroll
    for (int mi = 0; mi < 2; mi++) {
        #pragma unroll
        for (int ni = 0; ni < 8; ni++) {
            int col = wc * 128 + ni * 16 + lm;
            float b = bR[col];
            #pragma unroll
            for (int r = 0; r < 4; r++) {
                int row = wr * 32 + mi * 16 + quad * 4 + r;
                float v = fmaxf(acc1[mi][ni][r] + b, 0.f);
                Hs[hs_off(row, col)] = (bf16_t)v;
            }
        }
    }
    __syncthreads();

    // ---- phase 2: highway GEMM + gate, per 128-col strip ----
    #pragma unroll
    for (int s = 0; s < 2; s++) {
        f32x4 acc2[16] = {};
        for (int t = 0; t < 8; t++) {
            bf16x8 af2 = *(const bf16x8*)&Hs[t * 2048 + frag_off(wave * 16 + lm, quad)];
            #pragma unroll
            for (int ni = 0; ni < 16; ni++) {
                int wrow = (ni < 8) ? (s * 128 + ni * 16 + lm)
                                    : (256 + s * 128 + (ni - 8) * 16 + lm);
                bf16x8 bfr = *(const bf16x8*)(Wht + (size_t)wrow * 256 + t * 32 + quad * 8);
                acc2[ni] = __builtin_amdgcn_mfma_f32_16x16x32_bf16(
                    af2, bfr, acc2[ni], 0, 0, 0);
            }
        }
        #pragma unroll
        for (int ni = 0; ni < 8; ni++) {
            int col = s * 128 + ni * 16 + lm;
            float bp  = bH[col];
            float bg2 = bH[256 + col];
            #pragma unroll
            for (int r = 0; r < 4; r++) {
                int row = wave * 16 + quad * 4 + r;
                int grow = m0 + row;
                if (grow < M) {
                    float p = acc2[ni][r] + bp;
                    float g = acc2[ni + 8][r] + bg2;
                    float sg = 1.0f / (1.0f + __expf(-g));
                    float hv = (float)Hs[hs_off(row, col)];
                    float v = sg * fmaxf(p, 0.f) + (1.0f - sg) * hv;
                    if (outf) outf[(size_t)grow * 256 + col] = v;
                    else      outb[(size_t)grow * ldo + ocol + col] = (bf16_t)v;
                }
            }
        }
    }
}

// ---------------- fused prep: 8 transposes (LDS-tiled) + bias + x->bf16 + cnt zero ----
__global__ void prep_all(
    const float* __restrict__ rel_w1, const float* __restrict__ loop_w1,
    const float* __restrict__ rel_w2, const float* __restrict__ loop_w2,
    const float* __restrict__ hp_w1,  const float* __restrict__ ht_w1,
    const float* __restrict__ hp_w2,  const float* __restrict__ ht_w2,
    bf16_t* __restrict__ W1t, bf16_t* __restrict__ W2t,
    bf16_t* __restrict__ Wh1t, bf16_t* __restrict__ Wh2t,
    const float* __restrict__ rb1, const float* __restrict__ lb1,
    const float* __restrict__ rb2, const float* __restrict__ lb2,
    const float* __restrict__ hpb1, const float* __restrict__ htb1,
    const float* __restrict__ hpb2, const float* __restrict__ htb2,
    float* __restrict__ bR1, float* __restrict__ bR2,
    float* __restrict__ bH1, float* __restrict__ bH2,
    const float* __restrict__ x, bf16_t* __restrict__ A1, int N,
    int* __restrict__ cnt, int NSEG, int cvb)
{
    __shared__ float sh[16][256];
    int b = blockIdx.x, tid = threadIdx.x;
    if (b < 184) {
        const float* W; bf16_t* Wt; int ldk, k0, n0, kb;
        if      (b < 32)  { W = rel_w1;  Wt = W1t;  ldk = 640;  k0 = 0;    n0 = 0;   kb = b; }
        else if (b < 40)  { W = loop_w1; Wt = W1t;  ldk = 640;  k0 = 512;  n0 = 0;   kb = b - 32; }
        else if (b < 104) { W = rel_w2;  Wt = W2t;  ldk = 1280; k0 = 0;    n0 = 0;   kb = b - 40; }
        else if (b < 120) { W = loop_w2; Wt = W2t;  ldk = 1280; k0 = 1024; n0 = 0;   kb = b - 104; }
        else if (b < 136) { W = hp_w1;   Wt = Wh1t; ldk = 256;  k0 = 0;    n0 = 0;   kb = b - 120; }
        else if (b < 152) { W = ht_w1;   Wt = Wh1t; ldk = 256;  k0 = 0;    n0 = 256; kb = b - 136; }
        else if (b < 168) { W = hp_w2;   Wt = Wh2t; ldk = 256;  k0 = 0;    n0 = 0;   kb = b - 152; }
        else              { W = ht_w2;   Wt = Wh2t; ldk = 256;  k0 = 0;    n0 = 256; kb = b - 168; }
        int kb16 = kb * 16;
        #pragma unroll
        for (int kk = 0; kk < 16; kk++)
            sh[kk][tid] = W[(size_t)(kb16 + kk) * 256 + tid];
        __syncthreads();
        bf16x8 o0, o1;
        #pragma unroll
        for (int j = 0; j < 8; j++) {
            o0[j] = (bf16_t)sh[j][tid];
            o1[j] = (bf16_t)sh[8 + j][tid];
        }
        bf16_t* p = Wt + (size_t)(n0 + tid) * ldk + k0 + kb16;
        *(bf16x8*)p = o0;
        *(bf16x8*)(p + 8) = o1;
    } else if (b == 184) {
        int t = tid;
        bR1[t] = rb1[t] + lb1[t];
        bR2[t] = rb2[t] + lb2[t];
        bH1[t] = hpb1[t]; bH1[256 + t] = htb1[t];
        bH2[t] = hpb2[t]; bH2[256 + t] = htb2[t];
    } else if (b < 185 + cvb) {
        int t = (b - 185) * 256 + tid;
        if (t < N * 32) {
            int row = t >> 5, c = (t & 31) << 2;
            f32x4 v = *(const f32x4*)(x + (size_t)row * 128 + c);
            bf16x4 o;
            o[0] = (bf16_t)v[0]; o[1] = (bf16_t)v[1]; o[2] = (bf16_t)v[2]; o[3] = (bf16_t)v[3];
            *(bf16x4*)(A1 + (size_t)row * 640 + 512 + c) = o;
        }
    } else {
        int t = ((b - 185 - cvb) * 256 + tid) * 4;   // NSEG is a multiple of 4
        if (t < NSEG) {
            i32x4 z = {0, 0, 0, 0};
            *(i32x4*)(cnt + t) = z;
        }
    }
}

// ---------------- CSR build ----------------
__global__ void count_k(const int* __restrict__ dst, const int* __restrict__ rel,
                        int* __restrict__ cnt, int E)
{
    int e = blockIdx.x * blockDim.x + threadIdx.x;
    if (e < E) atomicAdd(&cnt[dst[e] * 4 + rel[e]], 1);
}

__global__ void scan_partial(const int* __restrict__ cnt, int* __restrict__ offs,
                             int* __restrict__ chunkSums, int NSEG)
{
    __shared__ int sh[256];
    int t = threadIdx.x;
    int idx = blockIdx.x * 256 + t;
    int v = (idx < NSEG) ? cnt[idx] : 0;
    sh[t] = v;
    __syncthreads();
    for (int d = 1; d < 256; d <<= 1) {
        int add = (t >= d) ? sh[t - d] : 0;
        __syncthreads();
        sh[t] += add;
        __syncthreads();
    }
    if (idx < NSEG) offs[idx] = sh[t] - v;
    if (t == 255) chunkSums[blockIdx.x] = sh[t];
}

__global__ void scan_chunks(int* __restrict__ chunkSums, int NCHUNK)
{
    __shared__ int sh[1024];
    int t = threadIdx.x;
    int v = (t < NCHUNK) ? chunkSums[t] : 0;
    sh[t] = v;
    __syncthreads();
    for (int d = 1; d < 1024; d <<= 1) {
        int add = (t >= d) ? sh[t - d] : 0;
        __syncthreads();
        sh[t] += add;
        __syncthreads();
    }
    if (t < NCHUNK) chunkSums[t] = sh[t] - v;
}

__global__ void scan_add(int* __restrict__ offs, const int* __restrict__ chunkSums,
                         int* __restrict__ cursor, int NSEG)
{
    int idx = blockIdx.x * 256 + threadIdx.x;
    if (idx < NSEG) {
        int o = offs[idx] + chunkSums[blockIdx.x];
        offs[idx] = o;
        cursor[idx] = o;
    }
}

__global__ void fill_k(const int* __restrict__ src, const int* __restrict__ dst,
                       const int* __restrict__ rel,
                       int* __restrict__ cursor, int* __restrict__ eidx, int E)
{
    int e = blockIdx.x * blockDim.x + threadIdx.x;
    if (e < E) {
        int seg = dst[e] * 4 + rel[e];
        int pos = atomicAdd(&cursor[seg], 1);
        eidx[pos] = src[e];
    }
}

// ---------------- segment mean, D=256: half-wave/edge, bf16x8, 8-deep unroll ----
__global__ void seg_mean256(const int* __restrict__ offs, const int* __restrict__ cnt,
                            const int* __restrict__ eidx,
                            const bf16_t* __restrict__ xb, int ldx,
                            bf16_t* __restrict__ Aout, int lda, int NSEG)
{
    int wv = (blockIdx.x << 2) + (threadIdx.x >> 6);
    if (wv >= NSEG) return;
    int lane = threadIdx.x & 63;
    int half = lane >> 5;
    int c = (lane & 31) << 3;               // 32 lanes x 8 elems = 256 cols
    int start = offs[wv];
    int n = cnt[wv];
    float acc[8] = {};
    int i = 0;
    for (; i + 8 <= n; i += 8) {
        int s0 = eidx[start + i + 0 + half];
        int s1 = eidx[start + i + 2 + half];
        int s2 = eidx[start + i + 4 + half];
        int s3 = eidx[start + i + 6 + half];
        bf16x8 v0 = *(const bf16x8*)(xb + (size_t)s0 * ldx + c);
        bf16x8 v1 = *(const bf16x8*)(xb + (size_t)s1 * ldx + c);
        bf16x8 v2 = *(const bf16x8*)(xb + (size_t)s2 * ldx + c);
        bf16x8 v3 = *(const bf16x8*)(xb + (size_t)s3 * ldx + c);
        #pragma unroll
        for (int j = 0; j < 8; j++)
            acc[j] += ((float)v0[j] + (float)v1[j]) + ((float)v2[j] + (float)v3[j]);
    }
    for (; i + 2 <= n; i += 2) {
        int s = eidx[start + i + half];
        bf16x8 v = *(const bf16x8*)(xb + (size_t)s * ldx + c);
        #pragma unroll
        for (int j = 0; j < 8; j++) acc[j] += (float)v[j];
    }
    if (i < n && half == 0) {
        int s = eidx[start + i];
        bf16x8 v = *(const bf16x8*)(xb + (size_t)s * ldx + c);
        #pragma unroll
        for (int j = 0; j < 8; j++) acc[j] += (float)v[j];
    }
    #pragma unroll
    for (int j = 0; j < 8; j++) acc[j] += __shfl_xor(acc[j], 32, 64);
    if (half == 0) {
        float inv = 1.0f / ((float)n + 1e-10f);
        int node = wv >> 2, r = wv & 3;
        bf16x8 o;
        #pragma unroll
        for (int j = 0; j < 8; j++) o[j] = (bf16_t)(acc[j] * inv);
        *(bf16x8*)(Aout + (size_t)node * lda + r * 256 + c) = o;
    }
}

// ---------------- segment mean, D=128: quarter-wave/edge, bf16x8, 8-deep unroll ----
__global__ void seg_mean128(const int* __restrict__ offs, const int* __restrict__ cnt,
                            const int* __restrict__ eidx,
                            const bf16_t* __restrict__ xb, int ldx,
                            bf16_t* __restrict__ Aout, int lda, int NSEG)
{
    int wv = (blockIdx.x << 2) + (threadIdx.x >> 6);
    if (wv >= NSEG) return;
    int lane = threadIdx.x & 63;
    int q = lane >> 4;                      // quarter 0..3
    int c = (lane & 15) << 3;               // 16 lanes x 8 elems = 128 cols
    int start = offs[wv];
    int n = cnt[wv];
    float acc[8] = {};
    int i = 0;
    for (; i + 8 <= n; i += 8) {
        int s0 = eidx[start + i + q];
        int s1 = eidx[start + i + 4 + q];
        bf16x8 v0 = *(const bf16x8*)(xb + (size_t)s0 * ldx + c);
        bf16x8 v1 = *(const bf16x8*)(xb + (size_t)s1 * ldx + c);
        #pragma unroll
        for (int j = 0; j < 8; j++) acc[j] += (float)v0[j] + (float)v1[j];
    }
    for (; i + 4 <= n; i += 4) {
        int s = eidx[start + i + q];
        bf16x8 v = *(const bf16x8*)(xb + (size_t)s * ldx + c);
        #pragma unroll
        for (int j = 0; j < 8; j++) acc[j] += (float)v[j];
    }
    if (q < n - i) {
        int s = eidx[start + i + q];
        bf16x8 v = *(const bf16x8*)(xb + (size_t)s * ldx + c);
        #pragma unroll
        for (int j = 0; j < 8; j++) acc[j] += (float)v[j];
    }
    #pragma unroll
    for (int j = 0; j < 8; j++) {
        acc[j] += __shfl_xor(acc[j], 16, 64);
        acc[j] += __shfl_xor(acc[j], 32, 64);
    }
    if (lane < 16) {
        float inv = 1.0f / ((float)n + 1e-10f);
        int node = wv >> 2, r = wv & 3;
        bf16x8 o;
        #pragma unroll
        for (int j = 0; j < 8; j++) o[j] = (bf16_t)(acc[j] * inv);
        *(bf16x8*)(Aout + (size_t)node * lda + r * 128 + c) = o;
    }
}

extern "C" void kernel_launch(void* const* d_in, const int* in_sizes, int n_in,
                              void* d_out, int out_size, void* d_ws, size_t ws_size,
                              hipStream_t stream)
{
    const float* x       = (const float*)d_in[0];
    const int*   src     = (const int*)d_in[1];
    const int*   dst     = (const int*)d_in[2];
    const int*   rel     = (const int*)d_in[3];
    const float* rel_w1  = (const float*)d_in[4];
    const float* rel_b1  = (const float*)d_in[5];
    const float* loop_w1 = (const float*)d_in[6];
    const float* loop_b1 = (const float*)d_in[7];
    const float* hp_w1   = (const float*)d_in[8];
    const float* hp_b1   = (const float*)d_in[9];
    const float* ht_w1   = (const float*)d_in[10];
    const float* ht_b1   = (const float*)d_in[11];
    const float* rel_w2  = (const float*)d_in[12];
    const float* rel_b2  = (const float*)d_in[13];
    const float* loop_w2 = (const float*)d_in[14];
    const float* loop_b2 = (const float*)d_in[15];
    const float* hp_w2   = (const float*)d_in[16];
    const float* hp_b2   = (const float*)d_in[17];
    const float* ht_w2   = (const float*)d_in[18];
    const float* ht_b2   = (const float*)d_in[19];

    const int N = in_sizes[0] / 128;   // 50000
    const int E = in_sizes[1];         // 800000
    const int NSEG = N * 4;            // 200000
    const int NCHUNK = (NSEG + 255) / 256;   // 782
    float* out = (float*)d_out;

    char* ws = (char*)d_ws;
    size_t off = 0;
    auto alloc = [&](size_t bytes) {
        void* p = ws + off;
        off += (bytes + 255) & ~(size_t)255;
        return p;
    };
    int*    cnt    = (int*)alloc((size_t)NSEG * 4);
    int*    offs   = (int*)alloc((size_t)NSEG * 4);
    int*    cursor = (int*)alloc((size_t)NSEG * 4);
    int*    chunkS = (int*)alloc(4096);
    int*    eidx   = (int*)alloc((size_t)E * 4);
    bf16_t* A1     = (bf16_t*)alloc((size_t)N * 640 * 2);    // [update1 | x_bf16]
    bf16_t* A2     = (bf16_t*)alloc((size_t)N * 1280 * 2);   // [update2 | h1']
    bf16_t* W1t    = (bf16_t*)alloc((size_t)256 * 640 * 2);
    bf16_t* W2t    = (bf16_t*)alloc((size_t)256 * 1280 * 2);
    bf16_t* Wh1t   = (bf16_t*)alloc((size_t)512 * 256 * 2);
    bf16_t* Wh2t   = (bf16_t*)alloc((size_t)512 * 256 * 2);
    float*  bR1    = (float*)alloc(256 * 4);
    float*  bR2    = (float*)alloc(256 * 4);
    float*  bH1    = (float*)alloc(512 * 4);
    float*  bH2    = (float*)alloc(512 * 4);

    dim3 blk(256);
    const int NTM = (N + BM - 1) / BM;       // 782
    const int supers = (NTM + 7) / 8;        // 98
    const int gridF = supers * 8;            // 784

    // ---- fused prep: transposes + bias + x->bf16 + cnt zero (1 launch) ----
    const int cvb = (N * 32 + 255) / 256;            // convert blocks
    const int zb  = (NSEG / 4 + 255) / 256;          // zero blocks (NSEG % 4 == 0)
    prep_all<<<dim3(185 + cvb + zb), blk, 0, stream>>>(
        rel_w1, loop_w1, rel_w2, loop_w2, hp_w1, ht_w1, hp_w2, ht_w2,
        W1t, W2t, Wh1t, Wh2t,
        rel_b1, loop_b1, rel_b2, loop_b2, hp_b1, ht_b1, hp_b2, ht_b2,
        bR1, bR2, bH1, bH2,
        x, A1, N, cnt, NSEG, cvb);

    // ---- CSR build (shared by both layers) ----
    count_k<<<dim3((E + 255) / 256), blk, 0, stream>>>(dst, rel, cnt, E);
    scan_partial<<<dim3(NCHUNK), blk, 0, stream>>>(cnt, offs, chunkS, NSEG);
    scan_chunks<<<dim3(1), dim3(1024), 0, stream>>>(chunkS, NCHUNK);
    scan_add<<<dim3(NCHUNK), blk, 0, stream>>>(offs, chunkS, cursor, NSEG);
    fill_k<<<dim3((E + 255) / 256), blk, 0, stream>>>(src, dst, rel, cursor, eidx, E);

    // ---- layer 1 ----
    seg_mean128<<<dim3((NSEG + 3) / 4), blk, 0, stream>>>(offs, cnt, eidx,
                                                          A1 + 512, 640, A1, 640, NSEG);
    gemm_fused<<<dim3(gridF), blk, 0, stream>>>(A1, 640, N, 640, W1t, bR1,
                                                Wh1t, bH1,
                                                A2, 1280, 1024, nullptr, NTM);

    // ---- layer 2 ----
    seg_mean256<<<dim3((NSEG + 3) / 4), blk, 0, stream>>>(offs, cnt, eidx,
                                                          A2 + 1024, 1280, A2, 1280, NSEG);
    gemm_fused<<<dim3(gridF), blk, 0, stream>>>(A2, 1280, N, 1280, W2t, bR2,
                                                Wh2t, bH2,
                                                nullptr, 0, 0, out, NTM);
}

// Round 6
// 511.893 us; speedup vs baseline: 1.8336x; 1.8336x over previous
//
#include <hip/hip_runtime.h>

typedef __bf16 bf16_t;
typedef __bf16 bf16x8 __attribute__((ext_vector_type(8)));
typedef __bf16 bf16x4 __attribute__((ext_vector_type(4)));
typedef float f32x4 __attribute__((ext_vector_type(4)));
typedef int i32x4 __attribute__((ext_vector_type(4)));

#define BM 128
#define BK 64
// LDS layout: per row of 8 x 16B chunks, chunk cc is stored at slot (cc ^ (row&7)).
// DMA writes base + lane*16 contiguously (m104/m108): we permute WHICH global
// chunk each lane loads; fragment ds_read_b128s then spread over all 32 banks.

__device__ __forceinline__ void gload_lds16(const void* g, void* s) {
    __builtin_amdgcn_global_load_lds(
        (const __attribute__((address_space(1))) unsigned int*)g,
        (__attribute__((address_space(3))) unsigned int*)s, 16, 0, 0);
}

// ---------------- GEMM: C = A[M,K](bf16) * Bt[256,K]^T (bf16), fp32 acc ----------------
// Full 256-wide output per block (no column tiling -> A streamed exactly once).
// 4 waves: wave tile 64 rows x 128 cols, acc[4][8] = 128 VGPRs.
__global__ __launch_bounds__(256, 2) void gemm_k(
    const bf16_t* __restrict__ A, int lda, int M,
    const bf16_t* __restrict__ Bt, int K,
    const float* __restrict__ bias, int relu_flag,
    bf16_t* __restrict__ outb, int ldo, int ocol,
    int NTM)
{
    __shared__ __align__(16) bf16_t As[BM * BK];    // 16 KB
    __shared__ __align__(16) bf16_t Bs[256 * BK];   // 32 KB

    const int L   = blockIdx.x;
    const int xcd = L & 7;
    const int sup = L >> 3;
    const int mt  = sup * 8 + xcd;
    if (mt >= NTM) return;
    const int m0 = mt * BM;

    const int tid  = threadIdx.x;
    const int wave = tid >> 6, lane = tid & 63;
    const int wr   = wave >> 1, wc = wave & 1;
    const int lm   = lane & 15, quad = lane >> 4;

    const bf16_t* ag[4];
    const bf16_t* bg[8];
    #pragma unroll
    for (int j = 0; j < 4; j++) {
        int c   = j * 256 + tid;                  // A chunk 0..1023
        int row = c >> 3;                         // 0..127
        int col = ((c & 7) ^ (row & 7)) << 3;
        int gm  = m0 + row; if (gm >= M) gm = M - 1;
        ag[j] = A + (size_t)gm * lda + col;
    }
    #pragma unroll
    for (int j = 0; j < 8; j++) {
        int c   = j * 256 + tid;                  // B chunk 0..2047
        int row = c >> 3;                         // 0..255 = output col
        int col = ((c & 7) ^ (row & 7)) << 3;
        bg[j] = Bt + (size_t)row * K + col;
    }

    f32x4 acc[4][8] = {};

    for (int k0 = 0; k0 < K; k0 += BK) {
        __syncthreads();
        #pragma unroll
        for (int j = 0; j < 4; j++)
            gload_lds16(ag[j] + k0, As + (size_t)(j * 256 + tid) * 8);
        #pragma unroll
        for (int j = 0; j < 8; j++)
            gload_lds16(bg[j] + k0, Bs + (size_t)(j * 256 + tid) * 8);
        __syncthreads();

        #pragma unroll
        for (int h = 0; h < 2; h++) {
            bf16x8 af[4];
            #pragma unroll
            for (int i = 0; i < 4; i++) {
                int r = wr * 64 + i * 16 + lm;
                af[i] = *(const bf16x8*)&As[(size_t)(r * 8 + ((h * 4 + quad) ^ (r & 7))) * 8];
            }
            #pragma unroll
            for (int ni = 0; ni < 8; ni++) {
                int r = wc * 128 + ni * 16 + lm;
                bf16x8 bfr = *(const bf16x8*)&Bs[(size_t)(r * 8 + ((h * 4 + quad) ^ (r & 7))) * 8];
                #pragma unroll
                for (int mi = 0; mi < 4; mi++)
                    acc[mi][ni] = __builtin_amdgcn_mfma_f32_16x16x32_bf16(
                        af[mi], bfr, acc[mi][ni], 0, 0, 0);
            }
        }
    }

    #pragma unroll
    for (int mi = 0; mi < 4; mi++) {
        #pragma unroll
        for (int ni = 0; ni < 8; ni++) {
            int col = wc * 128 + ni * 16 + lm;
            float b = bias[col];
            #pragma unroll
            for (int r = 0; r < 4; r++) {
                int row = m0 + wr * 64 + mi * 16 + quad * 4 + r;
                if (row < M) {
                    float v = acc[mi][ni][r] + b;
                    if (relu_flag) v = fmaxf(v, 0.f);
                    outb[(size_t)row * ldo + ocol + col] = (bf16_t)v;
                }
            }
        }
    }
}

// ---------------- Fused highway GEMM+gate ----------------
// 2 strips of 128 cols (nt in 0..1). Bs rows: [hp rows nt*128..+127 | ht rows ditto].
// 4 waves x 32 rows, each wave does all 256 Bs-cols: acc[2][16] = 128 VGPRs.
// Epilogue gates in-register (P at ni, G at ni+8).
__global__ __launch_bounds__(256, 2) void gemm_hw2(
    const bf16_t* __restrict__ A, int M,          // h [M,256] bf16 (also skip input)
    const bf16_t* __restrict__ Bt,                // Wh [512,256] = [hp rows | ht rows]
    const float* __restrict__ bias,               // [512] = [hp bias | ht bias]
    bf16_t* __restrict__ outb, int ldo, int ocol,
    float* __restrict__ outf, int NTM)
{
    __shared__ __align__(16) bf16_t As[128 * 64];   // 16 KB
    __shared__ __align__(16) bf16_t Bs[256 * 64];   // 32 KB

    const int L    = blockIdx.x;
    const int xcd  = L & 7;
    const int rest = L >> 3;
    const int nt   = rest & 1;                    // 128-col strip
    const int sup  = rest >> 1;
    const int mt   = sup * 8 + xcd;
    if (mt >= NTM) return;
    const int m0 = mt * 128;

    const int tid  = threadIdx.x;
    const int wave = tid >> 6, lane = tid & 63;
    const int lm   = lane & 15, quad = lane >> 4;

    const bf16_t* ag[4];
    const bf16_t* bg[8];
    #pragma unroll
    for (int j = 0; j < 4; j++) {
        int c   = j * 256 + tid;
        int row = c >> 3;
        int col = ((c & 7) ^ (row & 7)) << 3;
        int gm  = m0 + row; if (gm >= M) gm = M - 1;
        ag[j] = A + (size_t)gm * 256 + col;
    }
    #pragma unroll
    for (int j = 0; j < 8; j++) {
        int c    = j * 256 + tid;
        int row  = c >> 3;                        // 0..255
        int col  = ((c & 7) ^ (row & 7)) << 3;
        int grow = nt * 128 + row + ((row >= 128) ? 128 : 0);  // hp strip | ht strip
        bg[j] = Bt + (size_t)grow * 256 + col;
    }

    f32x4 acc[2][16] = {};

    for (int k0 = 0; k0 < 256; k0 += 64) {
        __syncthreads();
        #pragma unroll
        for (int j = 0; j < 4; j++)
            gload_lds16(ag[j] + k0, As + (size_t)(j * 256 + tid) * 8);
        #pragma unroll
        for (int j = 0; j < 8; j++)
            gload_lds16(bg[j] + k0, Bs + (size_t)(j * 256 + tid) * 8);
        __syncthreads();

        #pragma unroll
        for (int h = 0; h < 2; h++) {
            bf16x8 af[2];
            #pragma unroll
            for (int i = 0; i < 2; i++) {
                int r = wave * 32 + i * 16 + lm;
                af[i] = *(const bf16x8*)&As[(size_t)(r * 8 + ((h * 4 + quad) ^ (r & 7))) * 8];
            }
            #pragma unroll
            for (int ni = 0; ni < 16; ni++) {
                int r = ni * 16 + lm;
                bf16x8 bfr = *(const bf16x8*)&Bs[(size_t)(r * 8 + ((h * 4 + quad) ^ (r & 7))) * 8];
                #pragma unroll
                for (int mi = 0; mi < 2; mi++)
                    acc[mi][ni] = __builtin_amdgcn_mfma_f32_16x16x32_bf16(
                        af[mi], bfr, acc[mi][ni], 0, 0, 0);
            }
        }
    }

    // epilogue: lane holds P (ni) and G (ni+8) for identical (row,col); gate here.
    #pragma unroll
    for (int mi = 0; mi < 2; mi++) {
        #pragma unroll
        for (int ni = 0; ni < 8; ni++) {
            int col = nt * 128 + ni * 16 + lm;    // 0..255
            float bp  = bias[col];
            float bg2 = bias[256 + col];
            #pragma unroll
            for (int r = 0; r < 4; r++) {
                int row = m0 + wave * 32 + mi * 16 + quad * 4 + r;
                if (row < M) {
                    float p = acc[mi][ni][r] + bp;
                    float g = acc[mi][ni + 8][r] + bg2;
                    float s = 1.0f / (1.0f + __expf(-g));
                    float hv = (float)A[(size_t)row * 256 + col];
                    float v = s * fmaxf(p, 0.f) + (1.0f - s) * hv;
                    if (outf) outf[(size_t)row * 256 + col] = v;
                    else      outb[(size_t)row * ldo + ocol + col] = (bf16_t)v;
                }
            }
        }
    }
}

// ---------------- fused prep: 8 transposes + bias + x->bf16 + cnt zero ----------------
__global__ void prep_all(
    const float* __restrict__ rel_w1, const float* __restrict__ loop_w1,
    const float* __restrict__ rel_w2, const float* __restrict__ loop_w2,
    const float* __restrict__ hp_w1,  const float* __restrict__ ht_w1,
    const float* __restrict__ hp_w2,  const float* __restrict__ ht_w2,
    bf16_t* __restrict__ W1t, bf16_t* __restrict__ W2t,
    bf16_t* __restrict__ Wh1t, bf16_t* __restrict__ Wh2t,
    const float* __restrict__ rb1, const float* __restrict__ lb1,
    const float* __restrict__ rb2, const float* __restrict__ lb2,
    const float* __restrict__ hpb1, const float* __restrict__ htb1,
    const float* __restrict__ hpb2, const float* __restrict__ htb2,
    float* __restrict__ bR1, float* __restrict__ bR2,
    float* __restrict__ bH1, float* __restrict__ bH2,
    const float* __restrict__ x, bf16_t* __restrict__ A1, int N,
    int* __restrict__ cnt, int NSEG, int cvb)
{
    int b = blockIdx.x, tid = threadIdx.x;
    if (b < 2944) {
        const float* W; bf16_t* Wt; int ldk, k0, n0, base;
        if      (b < 512)  { W = rel_w1;  Wt = W1t;  ldk = 640;  k0 = 0;    n0 = 0;   base = 0; }
        else if (b < 640)  { W = loop_w1; Wt = W1t;  ldk = 640;  k0 = 512;  n0 = 0;   base = 512; }
        else if (b < 1664) { W = rel_w2;  Wt = W2t;  ldk = 1280; k0 = 0;    n0 = 0;   base = 640; }
        else if (b < 1920) { W = loop_w2; Wt = W2t;  ldk = 1280; k0 = 1024; n0 = 0;   base = 1664; }
        else if (b < 2176) { W = hp_w1;   Wt = Wh1t; ldk = 256;  k0 = 0;    n0 = 0;   base = 1920; }
        else if (b < 2432) { W = ht_w1;   Wt = Wh1t; ldk = 256;  k0 = 0;    n0 = 256; base = 2176; }
        else if (b < 2688) { W = hp_w2;   Wt = Wh2t; ldk = 256;  k0 = 0;    n0 = 0;   base = 2432; }
        else               { W = ht_w2;   Wt = Wh2t; ldk = 256;  k0 = 0;    n0 = 256; base = 2688; }
        int k = b - base;       // one source row per block: coalesced 1 KB read
        int n = tid;
        Wt[(size_t)(n0 + n) * ldk + k0 + k] = (bf16_t)W[(size_t)k * 256 + n];
    } else if (b == 2944) {
        int t = tid;
        bR1[t] = rb1[t] + lb1[t];
        bR2[t] = rb2[t] + lb2[t];
        bH1[t] = hpb1[t]; bH1[256 + t] = htb1[t];
        bH2[t] = hpb2[t]; bH2[256 + t] = htb2[t];
    } else if (b < 2945 + cvb) {
        int t = (b - 2945) * 256 + tid;
        if (t < N * 32) {
            int row = t >> 5, c = (t & 31) << 2;
            f32x4 v = *(const f32x4*)(x + (size_t)row * 128 + c);
            bf16x4 o;
            o[0] = (bf16_t)v[0]; o[1] = (bf16_t)v[1]; o[2] = (bf16_t)v[2]; o[3] = (bf16_t)v[3];
            *(bf16x4*)(A1 + (size_t)row * 640 + 512 + c) = o;
        }
    } else {
        int t = ((b - 2945 - cvb) * 256 + tid) * 4;   // NSEG is a multiple of 4
        if (t < NSEG) {
            i32x4 z = {0, 0, 0, 0};
            *(i32x4*)(cnt + t) = z;
        }
    }
}

// ---------------- CSR build ----------------
__global__ void count_k(const int* __restrict__ dst, const int* __restrict__ rel,
                        int* __restrict__ cnt, int E)
{
    int e = blockIdx.x * blockDim.x + threadIdx.x;
    if (e < E) atomicAdd(&cnt[dst[e] * 4 + rel[e]], 1);
}

__global__ void scan_partial(const int* __restrict__ cnt, int* __restrict__ offs,
                             int* __restrict__ chunkSums, int NSEG)
{
    __shared__ int sh[256];
    int t = threadIdx.x;
    int idx = blockIdx.x * 256 + t;
    int v = (idx < NSEG) ? cnt[idx] : 0;
    sh[t] = v;
    __syncthreads();
    for (int d = 1; d < 256; d <<= 1) {
        int add = (t >= d) ? sh[t - d] : 0;
        __syncthreads();
        sh[t] += add;
        __syncthreads();
    }
    if (idx < NSEG) offs[idx] = sh[t] - v;
    if (t == 255) chunkSums[blockIdx.x] = sh[t];
}

__global__ void scan_chunks(int* __restrict__ chunkSums, int NCHUNK)
{
    __shared__ int sh[1024];
    int t = threadIdx.x;
    int v = (t < NCHUNK) ? chunkSums[t] : 0;
    sh[t] = v;
    __syncthreads();
    for (int d = 1; d < 1024; d <<= 1) {
        int add = (t >= d) ? sh[t - d] : 0;
        __syncthreads();
        sh[t] += add;
        __syncthreads();
    }
    if (t < NCHUNK) chunkSums[t] = sh[t] - v;
}

__global__ void scan_add(int* __restrict__ offs, const int* __restrict__ chunkSums,
                         int* __restrict__ cursor, int NSEG)
{
    int idx = blockIdx.x * 256 + threadIdx.x;
    if (idx < NSEG) {
        int o = offs[idx] + chunkSums[blockIdx.x];
        offs[idx] = o;
        cursor[idx] = o;
    }
}

__global__ void fill_k(const int* __restrict__ src, const int* __restrict__ dst,
                       const int* __restrict__ rel,
                       int* __restrict__ cursor, int* __restrict__ eidx, int E)
{
    int e = blockIdx.x * blockDim.x + threadIdx.x;
    if (e < E) {
        int seg = dst[e] * 4 + rel[e];
        int pos = atomicAdd(&cursor[seg], 1);
        eidx[pos] = src[e];
    }
}

// ---------------- segment mean, D=256: half-wave/edge, bf16x8, 8-deep unroll ----
__global__ void seg_mean256(const int* __restrict__ offs, const int* __restrict__ cnt,
                            const int* __restrict__ eidx,
                            const bf16_t* __restrict__ xb, int ldx,
                            bf16_t* __restrict__ Aout, int lda, int NSEG)
{
    int wv = (blockIdx.x << 2) + (threadIdx.x >> 6);
    if (wv >= NSEG) return;
    int lane = threadIdx.x & 63;
    int half = lane >> 5;
    int c = (lane & 31) << 3;               // 32 lanes x 8 elems = 256 cols
    int start = offs[wv];
    int n = cnt[wv];
    float acc[8] = {};
    int i = 0;
    for (; i + 8 <= n; i += 8) {
        int s0 = eidx[start + i + 0 + half];
        int s1 = eidx[start + i + 2 + half];
        int s2 = eidx[start + i + 4 + half];
        int s3 = eidx[start + i + 6 + half];
        bf16x8 v0 = *(const bf16x8*)(xb + (size_t)s0 * ldx + c);
        bf16x8 v1 = *(const bf16x8*)(xb + (size_t)s1 * ldx + c);
        bf16x8 v2 = *(const bf16x8*)(xb + (size_t)s2 * ldx + c);
        bf16x8 v3 = *(const bf16x8*)(xb + (size_t)s3 * ldx + c);
        #pragma unroll
        for (int j = 0; j < 8; j++)
            acc[j] += ((float)v0[j] + (float)v1[j]) + ((float)v2[j] + (float)v3[j]);
    }
    for (; i + 2 <= n; i += 2) {
        int s = eidx[start + i + half];
        bf16x8 v = *(const bf16x8*)(xb + (size_t)s * ldx + c);
        #pragma unroll
        for (int j = 0; j < 8; j++) acc[j] += (float)v[j];
    }
    if (i < n && half == 0) {
        int s = eidx[start + i];
        bf16x8 v = *(const bf16x8*)(xb + (size_t)s * ldx + c);
        #pragma unroll
        for (int j = 0; j < 8; j++) acc[j] += (float)v[j];
    }
    #pragma unroll
    for (int j = 0; j < 8; j++) acc[j] += __shfl_xor(acc[j], 32, 64);
    if (half == 0) {
        float inv = 1.0f / ((float)n + 1e-10f);
        int node = wv >> 2, r = wv & 3;
        bf16x8 o;
        #pragma unroll
        for (int j = 0; j < 8; j++) o[j] = (bf16_t)(acc[j] * inv);
        *(bf16x8*)(Aout + (size_t)node * lda + r * 256 + c) = o;
    }
}

// ---------------- segment mean, D=128: quarter-wave/edge, bf16x8, 8-deep unroll ----
__global__ void seg_mean128(const int* __restrict__ offs, const int* __restrict__ cnt,
                            const int* __restrict__ eidx,
                            const bf16_t* __restrict__ xb, int ldx,
                            bf16_t* __restrict__ Aout, int lda, int NSEG)
{
    int wv = (blockIdx.x << 2) + (threadIdx.x >> 6);
    if (wv >= NSEG) return;
    int lane = threadIdx.x & 63;
    int q = lane >> 4;                      // quarter 0..3
    int c = (lane & 15) << 3;               // 16 lanes x 8 elems = 128 cols
    int start = offs[wv];
    int n = cnt[wv];
    float acc[8] = {};
    int i = 0;
    for (; i + 8 <= n; i += 8) {
        int s0 = eidx[start + i + q];
        int s1 = eidx[start + i + 4 + q];
        bf16x8 v0 = *(const bf16x8*)(xb + (size_t)s0 * ldx + c);
        bf16x8 v1 = *(const bf16x8*)(xb + (size_t)s1 * ldx + c);
        #pragma unroll
        for (int j = 0; j < 8; j++) acc[j] += (float)v0[j] + (float)v1[j];
    }
    for (; i + 4 <= n; i += 4) {
        int s = eidx[start + i + q];
        bf16x8 v = *(const bf16x8*)(xb + (size_t)s * ldx + c);
        #pragma unroll
        for (int j = 0; j < 8; j++) acc[j] += (float)v[j];
    }
    if (q < n - i) {
        int s = eidx[start + i + q];
        bf16x8 v = *(const bf16x8*)(xb + (size_t)s * ldx + c);
        #pragma unroll
        for (int j = 0; j < 8; j++) acc[j] += (float)v[j];
    }
    #pragma unroll
    for (int j = 0; j < 8; j++) {
        acc[j] += __shfl_xor(acc[j], 16, 64);
        acc[j] += __shfl_xor(acc[j], 32, 64);
    }
    if (lane < 16) {
        float inv = 1.0f / ((float)n + 1e-10f);
        int node = wv >> 2, r = wv & 3;
        bf16x8 o;
        #pragma unroll
        for (int j = 0; j < 8; j++) o[j] = (bf16_t)(acc[j] * inv);
        *(bf16x8*)(Aout + (size_t)node * lda + r * 128 + c) = o;
    }
}

extern "C" void kernel_launch(void* const* d_in, const int* in_sizes, int n_in,
                              void* d_out, int out_size, void* d_ws, size_t ws_size,
                              hipStream_t stream)
{
    const float* x       = (const float*)d_in[0];
    const int*   src     = (const int*)d_in[1];
    const int*   dst     = (const int*)d_in[2];
    const int*   rel     = (const int*)d_in[3];
    const float* rel_w1  = (const float*)d_in[4];
    const float* rel_b1  = (const float*)d_in[5];
    const float* loop_w1 = (const float*)d_in[6];
    const float* loop_b1 = (const float*)d_in[7];
    const float* hp_w1   = (const float*)d_in[8];
    const float* hp_b1   = (const float*)d_in[9];
    const float* ht_w1   = (const float*)d_in[10];
    const float* ht_b1   = (const float*)d_in[11];
    const float* rel_w2  = (const float*)d_in[12];
    const float* rel_b2  = (const float*)d_in[13];
    const float* loop_w2 = (const float*)d_in[14];
    const float* loop_b2 = (const float*)d_in[15];
    const float* hp_w2   = (const float*)d_in[16];
    const float* hp_b2   = (const float*)d_in[17];
    const float* ht_w2   = (const float*)d_in[18];
    const float* ht_b2   = (const float*)d_in[19];

    const int N = in_sizes[0] / 128;   // 50000
    const int E = in_sizes[1];         // 800000
    const int NSEG = N * 4;            // 200000
    const int NCHUNK = (NSEG + 255) / 256;   // 782
    float* out = (float*)d_out;

    char* ws = (char*)d_ws;
    size_t off = 0;
    auto alloc = [&](size_t bytes) {
        void* p = ws + off;
        off += (bytes + 255) & ~(size_t)255;
        return p;
    };
    int*    cnt    = (int*)alloc((size_t)NSEG * 4);
    int*    offs   = (int*)alloc((size_t)NSEG * 4);
    int*    cursor = (int*)alloc((size_t)NSEG * 4);
    int*    chunkS = (int*)alloc(4096);
    int*    eidx   = (int*)alloc((size_t)E * 4);
    bf16_t* A1     = (bf16_t*)alloc((size_t)N * 640 * 2);    // [update1 | x_bf16]
    bf16_t* A2     = (bf16_t*)alloc((size_t)N * 1280 * 2);   // [update2 | h1']
    bf16_t* h      = (bf16_t*)alloc((size_t)N * 256 * 2);
    bf16_t* W1t    = (bf16_t*)alloc((size_t)256 * 640 * 2);
    bf16_t* W2t    = (bf16_t*)alloc((size_t)256 * 1280 * 2);
    bf16_t* Wh1t   = (bf16_t*)alloc((size_t)512 * 256 * 2);
    bf16_t* Wh2t   = (bf16_t*)alloc((size_t)512 * 256 * 2);
    float*  bR1    = (float*)alloc(256 * 4);
    float*  bR2    = (float*)alloc(256 * 4);
    float*  bH1    = (float*)alloc(512 * 4);
    float*  bH2    = (float*)alloc(512 * 4);

    dim3 blk(256);
    const int NTM = (N + BM - 1) / BM;       // 391
    const int supers = (NTM + 7) / 8;        // 49
    const int gridRGC = supers * 8;          // 392 (full 256-wide blocks)
    const int gridHW  = supers * 8 * 2;      // 784 (2 strips of 128 P+G cols)

    // ---- fused prep: transposes + bias + x->bf16 + cnt zero (1 launch) ----
    const int cvb = (N * 32 + 255) / 256;            // convert blocks
    const int zb  = (NSEG / 4 + 255) / 256;          // zero blocks (NSEG % 4 == 0)
    prep_all<<<dim3(2945 + cvb + zb), blk, 0, stream>>>(
        rel_w1, loop_w1, rel_w2, loop_w2, hp_w1, ht_w1, hp_w2, ht_w2,
        W1t, W2t, Wh1t, Wh2t,
        rel_b1, loop_b1, rel_b2, loop_b2, hp_b1, ht_b1, hp_b2, ht_b2,
        bR1, bR2, bH1, bH2,
        x, A1, N, cnt, NSEG, cvb);

    // ---- CSR build (shared by both layers) ----
    count_k<<<dim3((E + 255) / 256), blk, 0, stream>>>(dst, rel, cnt, E);
    scan_partial<<<dim3(NCHUNK), blk, 0, stream>>>(cnt, offs, chunkS, NSEG);
    scan_chunks<<<dim3(1), dim3(1024), 0, stream>>>(chunkS, NCHUNK);
    scan_add<<<dim3(NCHUNK), blk, 0, stream>>>(offs, chunkS, cursor, NSEG);
    fill_k<<<dim3((E + 255) / 256), blk, 0, stream>>>(src, dst, rel, cursor, eidx, E);

    // ---- layer 1 ----
    seg_mean128<<<dim3((NSEG + 3) / 4), blk, 0, stream>>>(offs, cnt, eidx,
                                                          A1 + 512, 640, A1, 640, NSEG);
    gemm_k<<<dim3(gridRGC), blk, 0, stream>>>(A1, 640, N, W1t, 640,
                                              bR1, 1, h, 256, 0, NTM);
    gemm_hw2<<<dim3(gridHW), blk, 0, stream>>>(h, N, Wh1t, bH1,
                                               A2, 1280, 1024, nullptr, NTM);

    // ---- layer 2 ----
    seg_mean256<<<dim3((NSEG + 3) / 4), blk, 0, stream>>>(offs, cnt, eidx,
                                                          A2 + 1024, 1280, A2, 1280, NSEG);
    gemm_k<<<dim3(gridRGC), blk, 0, stream>>>(A2, 1280, N, W2t, 1280,
                                              bR2, 1, h, 256, 0, NTM);
    gemm_hw2<<<dim3(gridHW), blk, 0, stream>>>(h, N, Wh2t, bH2,
                                               nullptr, 0, 0, out, NTM);
}